// Round 1
// baseline (2149.336 us; speedup 1.0000x reference)
//
#include <hip/hip_runtime.h>

#define IN_DIM 128
#define HID    64
#define OUTD   32

// ---------------- degree / norm ----------------

__global__ void k_init_deg(float* __restrict__ deg, int n) {
    int i = blockIdx.x * blockDim.x + threadIdx.x;
    if (i < n) deg[i] = 1.0f;   // self-loop
}

__global__ void k_count_deg(const int* __restrict__ dst, float* __restrict__ deg, int E) {
    int stride = gridDim.x * blockDim.x;
    for (int e = blockIdx.x * blockDim.x + threadIdx.x; e < E; e += stride)
        unsafeAtomicAdd(&deg[dst[e]], 1.0f);
}

__global__ void k_dinv(float* __restrict__ deg, int n) {
    int i = blockIdx.x * blockDim.x + threadIdx.x;
    if (i < n) deg[i] = rsqrtf(deg[i]);
}

// ---------------- layer 1 GEMM: hs1 = (x @ W1) * dinv[row]; agg1 seeded with self-loop ----------------
// 32 nodes / block, 256 threads. W1 (128x64, 32KB) + x rows (32x132 padded, ~16.9KB) in LDS.

__launch_bounds__(256)
__global__ void k_gemm1(const float* __restrict__ x, const float* __restrict__ W1,
                        const float* __restrict__ dinv,
                        float* __restrict__ hs1, float* __restrict__ agg1) {
    __shared__ float Ws[IN_DIM * HID];     // row-major [k][f]
    __shared__ float xs[32 * 132];         // padded stride 132 to dodge bank conflicts
    const int t = threadIdx.x;
    const int base = blockIdx.x * 32;

    {   // load W1 (2048 float4, coalesced)
        const float4* s4 = (const float4*)W1;
        float4* d4 = (float4*)Ws;
        for (int i = t; i < IN_DIM * HID / 4; i += 256) d4[i] = s4[i];
    }
    {   // load 32 x-rows (1024 float4, coalesced), store padded
        const float4* s4 = (const float4*)(x + (size_t)base * IN_DIM);
        for (int i = t; i < 32 * IN_DIM / 4; i += 256) {
            float4 v = s4[i];
            int node = i >> 5;       // /32 float4 per row
            int k4   = i & 31;
            *(float4*)&xs[node * 132 + k4 * 4] = v;
        }
    }
    __syncthreads();

    const int fq = t & 15;     // float4 group: f = 4*fq .. 4*fq+3
    const int nl = t >> 4;     // 0..15 -> nodes nl and nl+16
    const float4* Wf4 = (const float4*)Ws;

    float4 a0 = {0,0,0,0}, a1 = {0,0,0,0};
    #pragma unroll 8
    for (int k = 0; k < IN_DIM; ++k) {
        float4 w = Wf4[k * 16 + fq];
        float x0 = xs[nl * 132 + k];
        float x1 = xs[(nl + 16) * 132 + k];
        a0.x += x0 * w.x; a0.y += x0 * w.y; a0.z += x0 * w.z; a0.w += x0 * w.w;
        a1.x += x1 * w.x; a1.y += x1 * w.y; a1.z += x1 * w.z; a1.w += x1 * w.w;
    }
    int n0 = base + nl, n1 = base + nl + 16;
    float d0 = dinv[n0], d1 = dinv[n1];
    a0.x *= d0; a0.y *= d0; a0.z *= d0; a0.w *= d0;
    a1.x *= d1; a1.y *= d1; a1.z *= d1; a1.w *= d1;
    *(float4*)&hs1 [(size_t)n0 * HID + fq * 4] = a0;
    *(float4*)&agg1[(size_t)n0 * HID + fq * 4] = a0;   // self-loop seed
    *(float4*)&hs1 [(size_t)n1 * HID + fq * 4] = a1;
    *(float4*)&agg1[(size_t)n1 * HID + fq * 4] = a1;
}

// ---------------- edge scatter, layer 1: agg1[dst] += hs1[src] (16 lanes/edge) ----------------

__launch_bounds__(256)
__global__ void k_scatter1(const int* __restrict__ src, const int* __restrict__ dst,
                           const float* __restrict__ hs1, float* __restrict__ agg1, int E) {
    int tid = blockIdx.x * 256 + threadIdx.x;
    int e = tid >> 4;
    if (e >= E) return;
    int lane = tid & 15;
    int s = src[e], d = dst[e];
    float4 v = ((const float4*)hs1)[(size_t)s * 16 + lane];
    float* out = agg1 + (size_t)d * HID + lane * 4;
    unsafeAtomicAdd(out + 0, v.x);
    unsafeAtomicAdd(out + 1, v.y);
    unsafeAtomicAdd(out + 2, v.z);
    unsafeAtomicAdd(out + 3, v.w);
}

// ---------------- layer 2 GEMM: L1 = relu(dinv*agg1 + b1); hs2 = (L1 @ W2) * dinv; d_out seeded ----------------
// 32 nodes / block, 256 threads. W2 (64x32, 8KB) + L1 rows (32x68 padded) in LDS.

__launch_bounds__(256)
__global__ void k_gemm2(const float* __restrict__ agg1, const float* __restrict__ W2,
                        const float* __restrict__ b1, const float* __restrict__ dinv,
                        float* __restrict__ hs2, float* __restrict__ outInit) {
    __shared__ float Ws[HID * OUTD];   // [k][f]
    __shared__ float L1s[32 * 68];     // padded stride 68
    const int t = threadIdx.x;
    const int base = blockIdx.x * 32;

    for (int i = t; i < HID * OUTD / 4; i += 256)
        ((float4*)Ws)[i] = ((const float4*)W2)[i];

    for (int e = t; e < 32 * HID; e += 256) {   // stage L1 rows (fused relu+bias+norm)
        int n_l = e >> 6, k = e & 63;
        int gn = base + n_l;
        float v = dinv[gn] * agg1[(size_t)gn * HID + k] + b1[k];
        L1s[n_l * 68 + k] = fmaxf(v, 0.0f);
    }
    __syncthreads();

    const int fq = t & 7;      // f = 4*fq .. 4*fq+3
    const int nl = t >> 3;     // 0..31
    float4 a = {0,0,0,0};
    #pragma unroll 8
    for (int k = 0; k < HID; ++k) {
        float4 w = ((const float4*)Ws)[k * 8 + fq];
        float xv = L1s[nl * 68 + k];
        a.x += xv * w.x; a.y += xv * w.y; a.z += xv * w.z; a.w += xv * w.w;
    }
    int n = base + nl;
    float d = dinv[n];
    a.x *= d; a.y *= d; a.z *= d; a.w *= d;
    *(float4*)&hs2    [(size_t)n * OUTD + fq * 4] = a;
    *(float4*)&outInit[(size_t)n * OUTD + fq * 4] = a;   // self-loop seed
}

// ---------------- edge scatter, layer 2: out[dst] += hs2[src] (8 lanes/edge) ----------------

__launch_bounds__(256)
__global__ void k_scatter2(const int* __restrict__ src, const int* __restrict__ dst,
                           const float* __restrict__ hs2, float* __restrict__ out, int E) {
    int tid = blockIdx.x * 256 + threadIdx.x;
    int e = tid >> 3;
    if (e >= E) return;
    int lane = tid & 7;
    int s = src[e], d = dst[e];
    float4 v = ((const float4*)hs2)[(size_t)s * 8 + lane];
    float* o = out + (size_t)d * OUTD + lane * 4;
    unsafeAtomicAdd(o + 0, v.x);
    unsafeAtomicAdd(o + 1, v.y);
    unsafeAtomicAdd(o + 2, v.z);
    unsafeAtomicAdd(o + 3, v.w);
}

// ---------------- final: out = relu(dinv*out + b2) ----------------

__global__ void k_final(float* __restrict__ out, const float* __restrict__ b2,
                        const float* __restrict__ dinv, int total) {
    int i = blockIdx.x * blockDim.x + threadIdx.x;
    if (i >= total) return;
    int node = i >> 5;   // /OUTD
    int f = i & 31;
    out[i] = fmaxf(dinv[node] * out[i] + b2[f], 0.0f);
}

// ---------------- launch ----------------

extern "C" void kernel_launch(void* const* d_in, const int* in_sizes, int n_in,
                              void* d_out, int out_size, void* d_ws, size_t ws_size,
                              hipStream_t stream) {
    const float* x  = (const float*)d_in[0];
    const int*   ei = (const int*)  d_in[1];
    const float* W1 = (const float*)d_in[2];
    const float* b1 = (const float*)d_in[3];
    const float* W2 = (const float*)d_in[4];
    const float* b2 = (const float*)d_in[5];

    const int N = in_sizes[0] / IN_DIM;   // 100000
    const int E = in_sizes[1] / 2;        // 1600000
    const int* srcI = ei;                 // edge_index[0]
    const int* dstI = ei + E;             // edge_index[1]
    float* out = (float*)d_out;

    float* dinv = (float*)d_ws;                       // N floats (deg -> dinv in place)
    float* bufA = dinv + 131072;                      // N*64 floats: hs1, later hs2
    float* bufB = bufA + (size_t)N * HID;             // N*64 floats: agg1

    k_init_deg <<<(N + 255) / 256, 256, 0, stream>>>(dinv, N);
    k_count_deg<<<2048, 256, 0, stream>>>(dstI, dinv, E);
    k_dinv     <<<(N + 255) / 256, 256, 0, stream>>>(dinv, N);

    k_gemm1    <<<N / 32, 256, 0, stream>>>(x, W1, dinv, bufA, bufB);
    k_scatter1 <<<(E * 16 + 255) / 256, 256, 0, stream>>>(srcI, dstI, bufA, bufB, E);

    k_gemm2    <<<N / 32, 256, 0, stream>>>(bufB, W2, b1, dinv, bufA, out);
    k_scatter2 <<<(E * 8 + 255) / 256, 256, 0, stream>>>(srcI, dstI, bufA, out, E);

    k_final    <<<(N * OUTD + 255) / 256, 256, 0, stream>>>(out, b2, dinv, N * OUTD);
}

// Round 2
// 346.597 us; speedup vs baseline: 6.2013x; 6.2013x over previous
//
#include <hip/hip_runtime.h>

#define IN_DIM 128
#define HID    64
#define OUTD   32

// ================= degree / norm =================

__global__ void k_hist(const int* __restrict__ dst, int* __restrict__ counts, int E) {
    int stride = gridDim.x * blockDim.x;
    for (int e = blockIdx.x * blockDim.x + threadIdx.x; e < E; e += stride)
        atomicAdd(&counts[dst[e]], 1);
}

__global__ void k_dinv(const int* __restrict__ counts, float* __restrict__ dinv, int n) {
    int i = blockIdx.x * blockDim.x + threadIdx.x;
    if (i < n) dinv[i] = rsqrtf((float)counts[i] + 1.0f);   // +1 self-loop
}

// ================= exclusive prefix scan (counts -> row_start) =================
// scan1: per-block (1024 elems) exclusive scan + block totals

__global__ void k_scan1(const int* __restrict__ counts, int* __restrict__ rs,
                        int* __restrict__ bsum, int n) {
    __shared__ int sd[256];
    int t = threadIdx.x;
    int base = blockIdx.x * 1024 + t * 4;
    int c0 = 0, c1 = 0, c2 = 0, c3 = 0;
    if (base + 0 < n) c0 = counts[base + 0];
    if (base + 1 < n) c1 = counts[base + 1];
    if (base + 2 < n) c2 = counts[base + 2];
    if (base + 3 < n) c3 = counts[base + 3];
    int s = c0 + c1 + c2 + c3;
    sd[t] = s;
    __syncthreads();
    for (int off = 1; off < 256; off <<= 1) {
        int v = (t >= off) ? sd[t - off] : 0;
        __syncthreads();
        sd[t] += v;
        __syncthreads();
    }
    int excl = sd[t] - s;
    if (base + 0 < n) rs[base + 0] = excl;
    if (base + 1 < n) rs[base + 1] = excl + c0;
    if (base + 2 < n) rs[base + 2] = excl + c0 + c1;
    if (base + 3 < n) rs[base + 3] = excl + c0 + c1 + c2;
    if (t == 255) bsum[blockIdx.x] = sd[255];
}

// scan2: exclusive scan of block sums (nb <= 256, single block)

__global__ void k_scan2(int* __restrict__ bsum, int nb) {
    __shared__ int sd[256];
    int t = threadIdx.x;
    int v = (t < nb) ? bsum[t] : 0;
    sd[t] = v;
    __syncthreads();
    for (int off = 1; off < 256; off <<= 1) {
        int u = (t >= off) ? sd[t - off] : 0;
        __syncthreads();
        sd[t] += u;
        __syncthreads();
    }
    if (t < nb) bsum[t] = sd[t] - v;
}

// scan3: add block offsets; also init cursor copy; rs[n] = E

__global__ void k_scan3(int* __restrict__ rs, const int* __restrict__ bsum,
                        int* __restrict__ cursor, int n, int E) {
    int i = blockIdx.x * blockDim.x + threadIdx.x;
    if (i < n) {
        int v = rs[i] + bsum[i >> 10];
        rs[i] = v;
        cursor[i] = v;
    } else if (i == n) {
        rs[n] = E;
    }
}

// ================= CSR fill: csr[pos] = src, grouped by dst =================

__global__ void k_fill(const int* __restrict__ src, const int* __restrict__ dst,
                       int* __restrict__ cursor, int* __restrict__ csr, int E) {
    int stride = gridDim.x * blockDim.x;
    for (int e = blockIdx.x * blockDim.x + threadIdx.x; e < E; e += stride) {
        int d = dst[e];
        int pos = atomicAdd(&cursor[d], 1);
        csr[pos] = src[e];
    }
}

// ================= layer 1 GEMM: hs1 = (x @ W1) * dinv[row] =================

__launch_bounds__(256)
__global__ void k_gemm1(const float* __restrict__ x, const float* __restrict__ W1,
                        const float* __restrict__ dinv, float* __restrict__ hs1) {
    __shared__ float Ws[IN_DIM * HID];     // [k][f]
    __shared__ float xs[32 * 132];         // padded stride
    const int t = threadIdx.x;
    const int base = blockIdx.x * 32;

    {
        const float4* s4 = (const float4*)W1;
        float4* d4 = (float4*)Ws;
        for (int i = t; i < IN_DIM * HID / 4; i += 256) d4[i] = s4[i];
    }
    {
        const float4* s4 = (const float4*)(x + (size_t)base * IN_DIM);
        for (int i = t; i < 32 * IN_DIM / 4; i += 256) {
            float4 v = s4[i];
            int node = i >> 5;
            int k4   = i & 31;
            *(float4*)&xs[node * 132 + k4 * 4] = v;
        }
    }
    __syncthreads();

    const int fq = t & 15;
    const int nl = t >> 4;
    const float4* Wf4 = (const float4*)Ws;

    float4 a0 = {0,0,0,0}, a1 = {0,0,0,0};
    #pragma unroll 8
    for (int k = 0; k < IN_DIM; ++k) {
        float4 w = Wf4[k * 16 + fq];
        float x0 = xs[nl * 132 + k];
        float x1 = xs[(nl + 16) * 132 + k];
        a0.x += x0 * w.x; a0.y += x0 * w.y; a0.z += x0 * w.z; a0.w += x0 * w.w;
        a1.x += x1 * w.x; a1.y += x1 * w.y; a1.z += x1 * w.z; a1.w += x1 * w.w;
    }
    int n0 = base + nl, n1 = base + nl + 16;
    float d0 = dinv[n0], d1 = dinv[n1];
    a0.x *= d0; a0.y *= d0; a0.z *= d0; a0.w *= d0;
    a1.x *= d1; a1.y *= d1; a1.z *= d1; a1.w *= d1;
    *(float4*)&hs1[(size_t)n0 * HID + fq * 4] = a0;
    *(float4*)&hs1[(size_t)n1 * HID + fq * 4] = a1;
}

// ================= CSR aggregation, layer 1: agg[n] = hs[n] + sum_{s in nbrs(n)} hs[s] =================
// 16 lanes per node (float4 each), no atomics.

__launch_bounds__(256)
__global__ void k_agg1(const float* __restrict__ hs, const int* __restrict__ rs,
                       const int* __restrict__ csr, float* __restrict__ agg, int N) {
    int tid = blockIdx.x * 256 + threadIdx.x;
    int node = tid >> 4;
    if (node >= N) return;
    int lane = tid & 15;
    const float4* h4 = (const float4*)hs;
    float4 a = h4[(size_t)node * 16 + lane];   // self-loop
    float4 b = {0,0,0,0};
    int i = rs[node], end = rs[node + 1];
    for (; i + 2 <= end; i += 2) {
        int s0 = csr[i], s1 = csr[i + 1];
        float4 v0 = h4[(size_t)s0 * 16 + lane];
        float4 v1 = h4[(size_t)s1 * 16 + lane];
        a.x += v0.x; a.y += v0.y; a.z += v0.z; a.w += v0.w;
        b.x += v1.x; b.y += v1.y; b.z += v1.z; b.w += v1.w;
    }
    if (i < end) {
        int s0 = csr[i];
        float4 v0 = h4[(size_t)s0 * 16 + lane];
        a.x += v0.x; a.y += v0.y; a.z += v0.z; a.w += v0.w;
    }
    a.x += b.x; a.y += b.y; a.z += b.z; a.w += b.w;
    ((float4*)agg)[(size_t)node * 16 + lane] = a;
}

// ================= layer 2 GEMM: L1 = relu(dinv*agg1 + b1); hs2 = (L1 @ W2) * dinv =================

__launch_bounds__(256)
__global__ void k_gemm2(const float* __restrict__ agg1, const float* __restrict__ W2,
                        const float* __restrict__ b1, const float* __restrict__ dinv,
                        float* __restrict__ hs2) {
    __shared__ float Ws[HID * OUTD];
    __shared__ float L1s[32 * 68];
    const int t = threadIdx.x;
    const int base = blockIdx.x * 32;

    for (int i = t; i < HID * OUTD / 4; i += 256)
        ((float4*)Ws)[i] = ((const float4*)W2)[i];

    for (int e = t; e < 32 * HID; e += 256) {
        int n_l = e >> 6, k = e & 63;
        int gn = base + n_l;
        float v = dinv[gn] * agg1[(size_t)gn * HID + k] + b1[k];
        L1s[n_l * 68 + k] = fmaxf(v, 0.0f);
    }
    __syncthreads();

    const int fq = t & 7;
    const int nl = t >> 3;
    float4 a = {0,0,0,0};
    #pragma unroll 8
    for (int k = 0; k < HID; ++k) {
        float4 w = ((const float4*)Ws)[k * 8 + fq];
        float xv = L1s[nl * 68 + k];
        a.x += xv * w.x; a.y += xv * w.y; a.z += xv * w.z; a.w += xv * w.w;
    }
    int n = base + nl;
    float d = dinv[n];
    a.x *= d; a.y *= d; a.z *= d; a.w *= d;
    *(float4*)&hs2[(size_t)n * OUTD + fq * 4] = a;
}

// ================= CSR aggregation, layer 2 + fused epilogue: out = relu(dinv*sum + b2) =================
// 8 lanes per node (float4 each).

__launch_bounds__(256)
__global__ void k_agg2(const float* __restrict__ hs, const int* __restrict__ rs,
                       const int* __restrict__ csr, const float* __restrict__ dinv,
                       const float* __restrict__ b2, float* __restrict__ out, int N) {
    int tid = blockIdx.x * 256 + threadIdx.x;
    int node = tid >> 3;
    if (node >= N) return;
    int lane = tid & 7;
    const float4* h4 = (const float4*)hs;
    float4 a = h4[(size_t)node * 8 + lane];   // self-loop
    float4 b = {0,0,0,0};
    int i = rs[node], end = rs[node + 1];
    for (; i + 2 <= end; i += 2) {
        int s0 = csr[i], s1 = csr[i + 1];
        float4 v0 = h4[(size_t)s0 * 8 + lane];
        float4 v1 = h4[(size_t)s1 * 8 + lane];
        a.x += v0.x; a.y += v0.y; a.z += v0.z; a.w += v0.w;
        b.x += v1.x; b.y += v1.y; b.z += v1.z; b.w += v1.w;
    }
    if (i < end) {
        int s0 = csr[i];
        float4 v0 = h4[(size_t)s0 * 8 + lane];
        a.x += v0.x; a.y += v0.y; a.z += v0.z; a.w += v0.w;
    }
    float dn = dinv[node];
    float4 bb = ((const float4*)b2)[lane];
    float4 o;
    o.x = fmaxf((a.x + b.x) * dn + bb.x, 0.0f);
    o.y = fmaxf((a.y + b.y) * dn + bb.y, 0.0f);
    o.z = fmaxf((a.z + b.z) * dn + bb.z, 0.0f);
    o.w = fmaxf((a.w + b.w) * dn + bb.w, 0.0f);
    ((float4*)out)[(size_t)node * 8 + lane] = o;
}

// ================= launch =================

extern "C" void kernel_launch(void* const* d_in, const int* in_sizes, int n_in,
                              void* d_out, int out_size, void* d_ws, size_t ws_size,
                              hipStream_t stream) {
    const float* x  = (const float*)d_in[0];
    const int*   ei = (const int*)  d_in[1];
    const float* W1 = (const float*)d_in[2];
    const float* b1 = (const float*)d_in[3];
    const float* W2 = (const float*)d_in[4];
    const float* b2 = (const float*)d_in[5];

    const int N = in_sizes[0] / IN_DIM;   // 100000
    const int E = in_sizes[1] / 2;        // 1600000
    const int* srcI = ei;
    const int* dstI = ei + E;
    float* out = (float*)d_out;

    // workspace layout (512KB slots of 131072 elems)
    const size_t SLOT = 131072;
    float* dinv   = (float*)d_ws;                 // slot 0
    int*   counts = (int*)d_ws + SLOT * 1;        // slot 1
    int*   rs     = (int*)d_ws + SLOT * 2;        // slot 2 (N+1 ints)
    int*   cursor = (int*)d_ws + SLOT * 3;        // slot 3
    int*   bsum   = (int*)d_ws + SLOT * 4;        // slot 4 (<=256 ints)
    int*   csr    = (int*)d_ws + SLOT * 5;        // slots 5..17 (E ints)
    float* bufA   = (float*)d_ws + SLOT * 18;     // N*64 floats (hs1, later hs2)
    float* bufB   = bufA + (size_t)N * HID;       // N*64 floats (agg1)

    const int nScanBlocks = (N + 1023) / 1024;    // 98

    hipMemsetAsync(counts, 0, (size_t)N * sizeof(int), stream);
    k_hist <<<2048, 256, 0, stream>>>(dstI, counts, E);
    k_dinv <<<(N + 255) / 256, 256, 0, stream>>>(counts, dinv, N);
    k_scan1<<<nScanBlocks, 256, 0, stream>>>(counts, rs, bsum, N);
    k_scan2<<<1, 256, 0, stream>>>(bsum, nScanBlocks);
    k_scan3<<<(N + 1 + 255) / 256, 256, 0, stream>>>(rs, bsum, cursor, N, E);
    k_fill <<<2048, 256, 0, stream>>>(srcI, dstI, cursor, csr, E);

    k_gemm1<<<(N + 31) / 32, 256, 0, stream>>>(x, W1, dinv, bufA);
    k_agg1 <<<(N * 16 + 255) / 256, 256, 0, stream>>>(bufA, rs, csr, bufB, N);
    k_gemm2<<<(N + 31) / 32, 256, 0, stream>>>(bufB, W2, b1, dinv, bufA);
    k_agg2 <<<(N * 8 + 255) / 256, 256, 0, stream>>>(bufA, rs, csr, dinv, b2, out, N);
}

// Round 3
// 205.227 us; speedup vs baseline: 10.4730x; 1.6888x over previous
//
#include <hip/hip_runtime.h>

#define IN_DIM 128
#define HID    64
#define OUTD   32

#define BSHIFT 9
#define BNODES 512                 // 1 << BSHIFT
#define NB     196                 // ceil(100000 / 512)
#define CHUNK  4096                // edges per k_bscatter block

// ================= Pass A: coarse bucket counts =================

__launch_bounds__(256)
__global__ void k_bcount(const int* __restrict__ dst, int* __restrict__ bucketCnt, int E) {
    __shared__ int h[NB];
    int t = threadIdx.x;
    for (int i = t; i < NB; i += 256) h[i] = 0;
    __syncthreads();
    int stride = gridDim.x * blockDim.x;
    for (int e = blockIdx.x * blockDim.x + t; e < E; e += stride)
        atomicAdd(&h[dst[e] >> BSHIFT], 1);
    __syncthreads();
    for (int i = t; i < NB; i += 256)
        if (h[i]) atomicAdd(&bucketCnt[i], h[i]);
}

// ================= scan bucket counts -> bases & cursors =================

__global__ void k_bscan(const int* __restrict__ bucketCnt, int* __restrict__ bucketBase,
                        int* __restrict__ bucketCursor, int* __restrict__ rs, int N, int E) {
    __shared__ int sd[256];
    int t = threadIdx.x;
    int v = (t < NB) ? bucketCnt[t] : 0;
    sd[t] = v;
    __syncthreads();
    for (int off = 1; off < 256; off <<= 1) {
        int u = (t >= off) ? sd[t - off] : 0;
        __syncthreads();
        sd[t] += u;
        __syncthreads();
    }
    int excl = sd[t] - v;
    if (t < NB) { bucketBase[t] = excl; bucketCursor[t] = excl; }
    if (t == 0) { bucketBase[NB] = E; rs[N] = E; }
}

// ================= Pass B: scatter edges into buckets (packed src<<9 | dst_local) =================

__launch_bounds__(256)
__global__ void k_bscatter(const int* __restrict__ src, const int* __restrict__ dst,
                           int* __restrict__ bucketCursor, int* __restrict__ ebuf, int E) {
    __shared__ int h[NB];
    __shared__ int lbase[NB];
    __shared__ int lcur[NB];
    int t = threadIdx.x;
    int base = blockIdx.x * CHUNK;
    int end = min(base + CHUNK, E);
    for (int i = t; i < NB; i += 256) { h[i] = 0; lcur[i] = 0; }
    __syncthreads();
    for (int i = base + t; i < end; i += 256)
        atomicAdd(&h[dst[i] >> BSHIFT], 1);
    __syncthreads();
    for (int i = t; i < NB; i += 256)
        lbase[i] = h[i] ? atomicAdd(&bucketCursor[i], h[i]) : 0;
    __syncthreads();
    for (int i = base + t; i < end; i += 256) {
        int d = dst[i];
        int b = d >> BSHIFT;
        int off = atomicAdd(&lcur[b], 1);
        ebuf[lbase[b] + off] = (src[i] << BSHIFT) | (d & (BNODES - 1));
    }
}

// ================= Pass C: per-bucket fine CSR build + rs + dinv =================

__launch_bounds__(256)
__global__ void k_bfinal(const int* __restrict__ ebuf, const int* __restrict__ bucketBase,
                         int* __restrict__ rs, float* __restrict__ dinv,
                         int* __restrict__ csr, int N) {
    __shared__ int hist[BNODES];
    __shared__ int rsl[BNODES];
    __shared__ int ssum[256];
    int t = threadIdx.x;
    int b = blockIdx.x;
    int nodeBase = b << BSHIFT;
    int ebase = bucketBase[b], eend = bucketBase[b + 1];

    hist[t] = 0; hist[t + 256] = 0;
    __syncthreads();
    for (int i = ebase + t; i < eend; i += 256)
        atomicAdd(&hist[ebuf[i] & (BNODES - 1)], 1);
    __syncthreads();

    // exclusive scan of 512 histogram entries (2 per thread)
    int h0 = hist[2 * t], h1 = hist[2 * t + 1];
    ssum[t] = h0 + h1;
    __syncthreads();
    for (int off = 1; off < 256; off <<= 1) {
        int u = (t >= off) ? ssum[t - off] : 0;
        __syncthreads();
        ssum[t] += u;
        __syncthreads();
    }
    int excl = ssum[t] - h0 - h1;
    rsl[2 * t]     = excl;
    rsl[2 * t + 1] = excl + h0;

    int n0 = nodeBase + 2 * t, n1 = n0 + 1;
    if (n0 < N) { rs[n0] = ebase + excl;      dinv[n0] = rsqrtf((float)h0 + 1.0f); }
    if (n1 < N) { rs[n1] = ebase + excl + h0; dinv[n1] = rsqrtf((float)h1 + 1.0f); }

    hist[2 * t] = 0; hist[2 * t + 1] = 0;   // reuse as per-node cursors
    __syncthreads();

    for (int i = ebase + t; i < eend; i += 256) {
        int p = ebuf[i];
        int l = p & (BNODES - 1);
        int off = atomicAdd(&hist[l], 1);
        csr[ebase + rsl[l] + off] = ((unsigned)p) >> BSHIFT;
    }
}

// ================= layer 1 GEMM: hs1 = (x @ W1) * dinv[row] =================

__launch_bounds__(256)
__global__ void k_gemm1(const float* __restrict__ x, const float* __restrict__ W1,
                        const float* __restrict__ dinv, float* __restrict__ hs1) {
    __shared__ float Ws[IN_DIM * HID];     // [k][f]
    __shared__ float xs[32 * 132];         // padded stride
    const int t = threadIdx.x;
    const int base = blockIdx.x * 32;

    {
        const float4* s4 = (const float4*)W1;
        float4* d4 = (float4*)Ws;
        for (int i = t; i < IN_DIM * HID / 4; i += 256) d4[i] = s4[i];
    }
    {
        const float4* s4 = (const float4*)(x + (size_t)base * IN_DIM);
        for (int i = t; i < 32 * IN_DIM / 4; i += 256) {
            float4 v = s4[i];
            int node = i >> 5;
            int k4   = i & 31;
            *(float4*)&xs[node * 132 + k4 * 4] = v;
        }
    }
    __syncthreads();

    const int fq = t & 15;
    const int nl = t >> 4;
    const float4* Wf4 = (const float4*)Ws;

    float4 a0 = {0,0,0,0}, a1 = {0,0,0,0};
    #pragma unroll 8
    for (int k = 0; k < IN_DIM; ++k) {
        float4 w = Wf4[k * 16 + fq];
        float x0 = xs[nl * 132 + k];
        float x1 = xs[(nl + 16) * 132 + k];
        a0.x += x0 * w.x; a0.y += x0 * w.y; a0.z += x0 * w.z; a0.w += x0 * w.w;
        a1.x += x1 * w.x; a1.y += x1 * w.y; a1.z += x1 * w.z; a1.w += x1 * w.w;
    }
    int n0 = base + nl, n1 = base + nl + 16;
    float d0 = dinv[n0], d1 = dinv[n1];
    a0.x *= d0; a0.y *= d0; a0.z *= d0; a0.w *= d0;
    a1.x *= d1; a1.y *= d1; a1.z *= d1; a1.w *= d1;
    *(float4*)&hs1[(size_t)n0 * HID + fq * 4] = a0;
    *(float4*)&hs1[(size_t)n1 * HID + fq * 4] = a1;
}

// ================= CSR aggregation, layer 1 =================

__launch_bounds__(256)
__global__ void k_agg1(const float* __restrict__ hs, const int* __restrict__ rs,
                       const int* __restrict__ csr, float* __restrict__ agg, int N) {
    int tid = blockIdx.x * 256 + threadIdx.x;
    int node = tid >> 4;
    if (node >= N) return;
    int lane = tid & 15;
    const float4* h4 = (const float4*)hs;
    float4 a = h4[(size_t)node * 16 + lane];   // self-loop
    float4 b = {0,0,0,0};
    int i = rs[node], end = rs[node + 1];
    for (; i + 2 <= end; i += 2) {
        int s0 = csr[i], s1 = csr[i + 1];
        float4 v0 = h4[(size_t)s0 * 16 + lane];
        float4 v1 = h4[(size_t)s1 * 16 + lane];
        a.x += v0.x; a.y += v0.y; a.z += v0.z; a.w += v0.w;
        b.x += v1.x; b.y += v1.y; b.z += v1.z; b.w += v1.w;
    }
    if (i < end) {
        int s0 = csr[i];
        float4 v0 = h4[(size_t)s0 * 16 + lane];
        a.x += v0.x; a.y += v0.y; a.z += v0.z; a.w += v0.w;
    }
    a.x += b.x; a.y += b.y; a.z += b.z; a.w += b.w;
    ((float4*)agg)[(size_t)node * 16 + lane] = a;
}

// ================= layer 2 GEMM: L1 = relu(dinv*agg1 + b1); hs2 = (L1 @ W2) * dinv =================

__launch_bounds__(256)
__global__ void k_gemm2(const float* __restrict__ agg1, const float* __restrict__ W2,
                        const float* __restrict__ b1, const float* __restrict__ dinv,
                        float* __restrict__ hs2) {
    __shared__ float Ws[HID * OUTD];
    __shared__ float L1s[32 * 68];
    const int t = threadIdx.x;
    const int base = blockIdx.x * 32;

    for (int i = t; i < HID * OUTD / 4; i += 256)
        ((float4*)Ws)[i] = ((const float4*)W2)[i];

    for (int e = t; e < 32 * HID; e += 256) {
        int n_l = e >> 6, k = e & 63;
        int gn = base + n_l;
        float v = dinv[gn] * agg1[(size_t)gn * HID + k] + b1[k];
        L1s[n_l * 68 + k] = fmaxf(v, 0.0f);
    }
    __syncthreads();

    const int fq = t & 7;
    const int nl = t >> 3;
    float4 a = {0,0,0,0};
    #pragma unroll 8
    for (int k = 0; k < HID; ++k) {
        float4 w = ((const float4*)Ws)[k * 8 + fq];
        float xv = L1s[nl * 68 + k];
        a.x += xv * w.x; a.y += xv * w.y; a.z += xv * w.z; a.w += xv * w.w;
    }
    int n = base + nl;
    float d = dinv[n];
    a.x *= d; a.y *= d; a.z *= d; a.w *= d;
    *(float4*)&hs2[(size_t)n * OUTD + fq * 4] = a;
}

// ================= CSR aggregation, layer 2 + fused epilogue =================

__launch_bounds__(256)
__global__ void k_agg2(const float* __restrict__ hs, const int* __restrict__ rs,
                       const int* __restrict__ csr, const float* __restrict__ dinv,
                       const float* __restrict__ b2, float* __restrict__ out, int N) {
    int tid = blockIdx.x * 256 + threadIdx.x;
    int node = tid >> 3;
    if (node >= N) return;
    int lane = tid & 7;
    const float4* h4 = (const float4*)hs;
    float4 a = h4[(size_t)node * 8 + lane];   // self-loop
    float4 b = {0,0,0,0};
    int i = rs[node], end = rs[node + 1];
    for (; i + 2 <= end; i += 2) {
        int s0 = csr[i], s1 = csr[i + 1];
        float4 v0 = h4[(size_t)s0 * 8 + lane];
        float4 v1 = h4[(size_t)s1 * 8 + lane];
        a.x += v0.x; a.y += v0.y; a.z += v0.z; a.w += v0.w;
        b.x += v1.x; b.y += v1.y; b.z += v1.z; b.w += v1.w;
    }
    if (i < end) {
        int s0 = csr[i];
        float4 v0 = h4[(size_t)s0 * 8 + lane];
        a.x += v0.x; a.y += v0.y; a.z += v0.z; a.w += v0.w;
    }
    float dn = dinv[node];
    float4 bb = ((const float4*)b2)[lane];
    float4 o;
    o.x = fmaxf((a.x + b.x) * dn + bb.x, 0.0f);
    o.y = fmaxf((a.y + b.y) * dn + bb.y, 0.0f);
    o.z = fmaxf((a.z + b.z) * dn + bb.z, 0.0f);
    o.w = fmaxf((a.w + b.w) * dn + bb.w, 0.0f);
    ((float4*)out)[(size_t)node * 8 + lane] = o;
}

// ================= launch =================

extern "C" void kernel_launch(void* const* d_in, const int* in_sizes, int n_in,
                              void* d_out, int out_size, void* d_ws, size_t ws_size,
                              hipStream_t stream) {
    const float* x  = (const float*)d_in[0];
    const int*   ei = (const int*)  d_in[1];
    const float* W1 = (const float*)d_in[2];
    const float* b1 = (const float*)d_in[3];
    const float* W2 = (const float*)d_in[4];
    const float* b2 = (const float*)d_in[5];

    const int N = in_sizes[0] / IN_DIM;   // 100000
    const int E = in_sizes[1] / 2;        // 1600000
    const int* srcI = ei;
    const int* dstI = ei + E;
    float* out = (float*)d_out;

    // workspace layout (all offsets 16B-aligned)
    float* dinv         = (float*)d_ws;                       // 131072 slot
    int*   rs           = (int*)d_ws + 131072;                // N+1 (131072 slot)
    int*   bucketCnt    = rs + 131072;                        // 256
    int*   bucketBase   = bucketCnt + 256;                    // 256 (NB+1)
    int*   bucketCursor = bucketBase + 256;                   // 256
    int*   ebuf         = bucketCursor + 256;                 // E packed words
    int*   csr          = ebuf + E;                           // E
    float* bufA         = (float*)(csr + E);                  // N*HID (hs1, later hs2)
    float* bufB         = bufA + (size_t)N * HID;             // N*HID (agg1)

    hipMemsetAsync(bucketCnt, 0, NB * sizeof(int), stream);
    k_bcount  <<<256, 256, 0, stream>>>(dstI, bucketCnt, E);
    k_bscan   <<<1, 256, 0, stream>>>(bucketCnt, bucketBase, bucketCursor, rs, N, E);
    k_bscatter<<<(E + CHUNK - 1) / CHUNK, 256, 0, stream>>>(srcI, dstI, bucketCursor, ebuf, E);
    k_bfinal  <<<NB, 256, 0, stream>>>(ebuf, bucketBase, rs, dinv, csr, N);

    k_gemm1<<<(N + 31) / 32, 256, 0, stream>>>(x, W1, dinv, bufA);
    k_agg1 <<<(N * 16 + 255) / 256, 256, 0, stream>>>(bufA, rs, csr, bufB, N);
    k_gemm2<<<(N + 31) / 32, 256, 0, stream>>>(bufB, W2, b1, dinv, bufA);
    k_agg2 <<<(N * 8 + 255) / 256, 256, 0, stream>>>(bufA, rs, csr, dinv, b2, out, N);
}